// Round 12
// baseline (142.886 us; speedup 1.0000x reference)
//
#include <hip/hip_runtime.h>
#include <hip/hip_bf16.h>

#define NN 10000
#define NE 320000
#define CAP 96   // deg ~ Binom(320000,1e-4): mean 32, sd 5.66; P(overflow) < 1e-19

typedef __attribute__((ext_vector_type(8)))  __bf16 bf16x8;
typedef __attribute__((ext_vector_type(4)))  float  f32x4;

// ======================= bucket scatter =======================
__global__ void scatter_bucket_kernel(const int* __restrict__ eidx,
                                      int* __restrict__ cnt, int2* __restrict__ bucket) {
    for (int e = blockIdx.x * 256 + threadIdx.x; e < NE; e += gridDim.x * 256) {
        int d = eidx[NE + e];
        int s = eidx[e];
        int p = atomicAdd(&cnt[d], 1);
        if (p < CAP) bucket[d * CAP + p] = make_int2(e, s);
    }
}

// ======================= node-centric 16x16x32 edge kernel =======================
// One wave per dst node. Bias folded into the matmul: ea padded K 16->32 with
// eax[16]=1, Wext[16][c]=be[c], rest zero -> MFMA C operand is ZERO (the r11
// per-group 4xb128 bias reads are gone). Per 32-edge chunk: 64 channel-tiles
// (ct), each 1 shared A-read (b128, kgrp<2 lanes; u16 bias row for kgrp2) + 2
// MFMAs (two 16-edge subtiles). Inactive slots: zero the whole B-frag (incl.
// const-1) -> relu(0)=0, no consume masking.
//   A[m=lane&15][k=(lane>>4)*8+j] ; B[k=(lane>>4)*8+j][n=lane&15]
//   D: col=lane&15=edge, row=(lane>>4)*4+r = channel-in-tile
//   c = ct*16+row -> i = ct>>1 (xv component = cc>>1), o = (ct&1)*16+row
// SPILL TRAP (r5/r6, 0.7-2.7 GB scratch): keep ib loop RUNTIME (opaque start +
// unroll 1) so the 64 A-reads can't be hoisted chunk-invariantly.
// OCCUPANCY (r8-r11): LDS ~39KB x4 blocks = 157KB, VGPR target <=128 ->
// (256,4) = 16 waves/CU (~50%), up from 27%.
__global__ __launch_bounds__(256, 4) void edge_node_kernel(
    const float* __restrict__ x, const float* __restrict__ ea,
    const float* __restrict__ W, const float* __restrict__ be,
    const float* __restrict__ root, const float* __restrict__ bias,
    const int* __restrict__ cnt, const int2* __restrict__ bucket,
    float* __restrict__ out)
{
    __shared__ __attribute__((aligned(16))) __bf16 WT2[64][2][16][8]; // 32 KiB: W k=0..15
    __shared__ __attribute__((aligned(16))) __bf16 BRL[1024];         // 2 KiB: bias row k=16
    __shared__ __attribute__((aligned(16))) float  root_s[32][32];    // 4 KiB
    __shared__ float bias_s[32];
    __shared__ float msum[4][32];

    const int tid = threadIdx.x;

    for (int u = tid; u < 16384; u += 256) {
        int j = u & 7, cl = (u >> 3) & 15, kg = (u >> 7) & 1, ct = u >> 8;
        WT2[ct][kg][cl][j] = (__bf16)W[(kg * 8 + j) * 1024 + ct * 16 + cl];
    }
    for (int u = tid; u < 1024; u += 256) {
        BRL[u] = (__bf16)be[u];
        root_s[u >> 5][u & 31] = root[u];
    }
    if (tid < 32) bias_s[tid] = bias[tid];
    __syncthreads();

    const int lane = tid & 63;
    const int kgrp = lane >> 4;      // 0..3: k-slice of A/B fragments
    const int c16  = lane & 15;      // edge col (B,D) / channel row (A)
    const int w    = tid >> 6;
    const int n    = blockIdx.x * 4 + w;   // exact: gridDim.x = NN/4

    const int deg = cnt[n];
    const int2* bk = bucket + (size_t)n * CAP;

    float ms0[4] = {0.f, 0.f, 0.f, 0.f};   // even ct: channels o = kgrp*4+r
    float ms1[4] = {0.f, 0.f, 0.f, 0.f};   // odd  ct: channels o = 16+kgrp*4+r

    for (int c0 = 0; c0 < deg; c0 += 32) {
        const int i0 = c0 + c16, i1 = i0 + 16;
        const bool a0 = i0 < deg, a1 = i1 < deg;
        const int2 es0 = bk[a0 ? i0 : deg - 1];
        const int2 es1 = bk[a1 ? i1 : deg - 1];

        bf16x8 bf0 = {}, bf1 = {};
        if (kgrp < 2) {
            const f32x4* p0 = (const f32x4*)(ea + (size_t)es0.x * 16 + kgrp * 8);
            const f32x4* p1 = (const f32x4*)(ea + (size_t)es1.x * 16 + kgrp * 8);
            f32x4 u0 = p0[0], u1 = p0[1], v0 = p1[0], v1 = p1[1];
            bf0[0]=(__bf16)u0.x; bf0[1]=(__bf16)u0.y; bf0[2]=(__bf16)u0.z; bf0[3]=(__bf16)u0.w;
            bf0[4]=(__bf16)u1.x; bf0[5]=(__bf16)u1.y; bf0[6]=(__bf16)u1.z; bf0[7]=(__bf16)u1.w;
            bf1[0]=(__bf16)v0.x; bf1[1]=(__bf16)v0.y; bf1[2]=(__bf16)v0.z; bf1[3]=(__bf16)v0.w;
            bf1[4]=(__bf16)v1.x; bf1[5]=(__bf16)v1.y; bf1[6]=(__bf16)v1.z; bf1[7]=(__bf16)v1.w;
        } else if (kgrp == 2) {
            bf0[0] = (__bf16)1.0f;       // the const-1 feature at k=16
            bf1[0] = (__bf16)1.0f;
        }
        if (!a0) bf0 = (bf16x8){};       // zero B-frag => w=relu(0)=0 => no contribution
        if (!a1) bf1 = (bf16x8){};

        const f32x4* xp0 = (const f32x4*)(x + (size_t)es0.y * 32);
        const f32x4* xp1 = (const f32x4*)(x + (size_t)es1.y * 32);

        int ib0 = 0;
        asm volatile("" : "+v"(ib0));    // opaque start: no unroll, no LICM of A-reads
        f32x4 xq0 = xp0[0], xq1 = xp1[0];
        #pragma unroll 1
        for (int ib = ib0; ib < 8; ++ib) {
            f32x4 nx0 = xq0, nx1 = xq1;
            if (ib < 7) { nx0 = xp0[ib + 1]; nx1 = xp1[ib + 1]; }  // prefetch next i-block
            #pragma unroll
            for (int cc = 0; cc < 8; ++cc) {
                const int ct = ib * 8 + cc;
                bf16x8 af;
                if (kgrp < 2) {
                    af = *(const bf16x8*)(&WT2[ct][kgrp][c16][0]);
                } else {
                    af = (bf16x8){};
                    if (kgrp == 2) af[0] = BRL[ct * 16 + c16];   // bias row (k=16)
                }
                const f32x4 z = {0.0f, 0.0f, 0.0f, 0.0f};
                f32x4 A0 = __builtin_amdgcn_mfma_f32_16x16x32_bf16(af, bf0, z, 0, 0, 0);
                f32x4 A1 = __builtin_amdgcn_mfma_f32_16x16x32_bf16(af, bf1, z, 0, 0, 0);
                const float xv0 = (cc >> 1) == 0 ? xq0.x : (cc >> 1) == 1 ? xq0.y
                                : (cc >> 1) == 2 ? xq0.z : xq0.w;
                const float xv1 = (cc >> 1) == 0 ? xq1.x : (cc >> 1) == 1 ? xq1.y
                                : (cc >> 1) == 2 ? xq1.z : xq1.w;
                if (cc & 1) {
                    #pragma unroll
                    for (int r = 0; r < 4; ++r)
                        ms1[r] += fmaxf(A0[r], 0.0f) * xv0 + fmaxf(A1[r], 0.0f) * xv1;
                } else {
                    #pragma unroll
                    for (int r = 0; r < 4; ++r)
                        ms0[r] += fmaxf(A0[r], 0.0f) * xv0 + fmaxf(A1[r], 0.0f) * xv1;
                }
                if ((cc & 3) == 3) __builtin_amdgcn_sched_barrier(0);  // bound liveness
            }
            xq0 = nx0; xq1 = nx1;
        }
    }

    // reduce over the 16 edge-cols (masks 1..8 stay within each 16-lane group)
    #pragma unroll
    for (int mm = 1; mm <= 8; mm <<= 1) {
        #pragma unroll
        for (int r = 0; r < 4; ++r) {
            ms0[r] += __shfl_xor(ms0[r], mm, 64);
            ms1[r] += __shfl_xor(ms1[r], mm, 64);
        }
    }

    const float rdeg = (deg > 0) ? (1.0f / (float)deg) : 0.0f;
    if (c16 == 0) {
        #pragma unroll
        for (int r = 0; r < 4; ++r) {
            msum[w][kgrp * 4 + r]      = ms0[r] * rdeg;
            msum[w][16 + kgrp * 4 + r] = ms1[r] * rdeg;
        }
    }
    __syncthreads();

    // epilogue: out[n][o] = mean_msg[o] + bias[o] + sum_i x[n][i]*root[i][o]
    const int hi  = lane >> 5;
    const int l31 = lane & 31;
    const float xv = x[(size_t)n * 32 + l31];
    if (hi == 0) {
        float m = msum[w][l31] + bias_s[l31];
        #pragma unroll
        for (int i = 0; i < 32; ++i)
            m += __shfl(xv, i, 64) * root_s[i][l31];
        out[(size_t)n * 32 + l31] = m;
    }
}

// ======================= launch =======================
extern "C" void kernel_launch(void* const* d_in, const int* in_sizes, int n_in,
                              void* d_out, int out_size, void* d_ws, size_t ws_size,
                              hipStream_t stream) {
    const float* x    = (const float*)d_in[0];
    const int*   eidx = (const int*)d_in[1];     // [2][NE]
    const float* ea   = (const float*)d_in[2];   // [NE][16]
    const float* W    = (const float*)d_in[3];   // [16][1024]
    const float* be   = (const float*)d_in[4];   // [1024]
    const float* root = (const float*)d_in[5];   // [32][32]
    const float* bias = (const float*)d_in[6];   // [32]
    float* out = (float*)d_out;

    // ws: cnt[NN] ints | bucket int2[NN*CAP]
    int*  cnt    = (int*)d_ws;
    int2* bucket = (int2*)((char*)d_ws + ((NN * 4 + 15) & ~15));

    hipMemsetAsync(cnt, 0, NN * sizeof(int), stream);
    scatter_bucket_kernel<<<640, 256, 0, stream>>>(eidx, cnt, bucket);
    edge_node_kernel<<<NN / 4, 256, 0, stream>>>(x, ea, W, be, root, bias,
                                                 cnt, bucket, out);
}

// Round 13
// 105.194 us; speedup vs baseline: 1.3583x; 1.3583x over previous
//
#include <hip/hip_runtime.h>
#include <hip/hip_bf16.h>

#define NN 10000
#define NE 320000
#define CAP 96   // deg ~ Binom(320000,1e-4): mean 32, sd 5.66; P(overflow) < 1e-19

typedef __attribute__((ext_vector_type(8)))  __bf16 bf16x8;
typedef __attribute__((ext_vector_type(16))) float  f32x16;
typedef __attribute__((ext_vector_type(4)))  float  f32x4;

// ======================= bucket scatter + W->bf16 prep =======================
// blocks 0..639: group edges by dst (one 8B int2 store per edge).
// block 640: convert W (16x1024 f32) to bf16 in the af-fragment layout:
//   wbf[g*512 + hi*256 + c*8 + j] = bf16(W[(hi*8+j)*1024 + g*32 + c])
// so a lane's af read is 16B contiguous, coalesced across l31.
__global__ void scatter_bucket_kernel(const int* __restrict__ eidx,
                                      int* __restrict__ cnt, int2* __restrict__ bucket,
                                      const float* __restrict__ W, __bf16* __restrict__ wbf) {
    if (blockIdx.x == 640) {
        for (int u = threadIdx.x; u < 16384; u += 256) {
            int j = u & 7, c = (u >> 3) & 31, hi = (u >> 8) & 1, g = u >> 9;
            wbf[u] = (__bf16)W[(hi * 8 + j) * 1024 + g * 32 + c];
        }
        return;
    }
    for (int e = blockIdx.x * 256 + threadIdx.x; e < NE; e += 640 * 256) {
        int d = eidx[NE + e];
        int s = eidx[e];
        int p = atomicAdd(&cnt[d], 1);
        if (p < CAP) bucket[d * CAP + p] = make_int2(e, s);
    }
}

// ======================= node-centric fused edge + epilogue kernel =======================
// One wave per dst node n; 32-edge chunks through MFMA 32x32x16 bf16
// (A = W_edge cols, B = edge_attr rows, C = permuted bias). r13 change vs r11:
// af comes from GLOBAL (bf16 W copy, 32KB chip-wide -> L2-resident) instead of
// a 32KB LDS stage. LDS drops 42->9KB so occupancy is VGPR-bound: (256,4)
// gives 16 waves/CU (~50%) vs r11's 27%. ci stays LDS broadcast (4KB).
//
// SPILL TRAP (r5/r6, 0.7-2.7 GB scratch): opaque base per chunk so neither
// the 32 af global loads nor the ci reads can be hoisted chunk-invariantly;
// sched_barrier(0) every 2nd group caps liveness at ~2 acc tiles (r10-proven).
__global__ __launch_bounds__(256, 4) void edge_node_kernel(
    const float* __restrict__ x, const float* __restrict__ ea,
    const __bf16* __restrict__ wbf, const float* __restrict__ be,
    const float* __restrict__ root, const float* __restrict__ bias,
    const int* __restrict__ cnt, const int2* __restrict__ bucket,
    float* __restrict__ out)
{
    __shared__ __attribute__((aligned(16))) float BPF[32][2][16];   // 4 KiB permuted bias
    __shared__ __attribute__((aligned(16))) float root_s[32][32];   // 4 KiB
    __shared__ float bias_s[32];
    __shared__ float msum[4][32];

    const int tid = threadIdx.x;

    #pragma unroll
    for (int k = 0; k < 4; ++k) {
        int idx = tid + k * 256;              // (cb, hi, r) + root staging
        int cb = idx >> 5, rem = idx & 31, hi2 = rem >> 4, r = rem & 15;
        int row = (r & 3) + 8 * (r >> 2) + 4 * hi2;
        BPF[cb][hi2][r] = be[cb * 32 + row];
        root_s[idx >> 5][idx & 31] = root[idx];
    }
    if (tid < 32) bias_s[tid] = bias[tid];
    __syncthreads();

    const int lane = tid & 63;
    const int hi   = lane >> 5;
    const int l31  = lane & 31;
    const int w    = tid >> 6;
    const int n    = blockIdx.x * 4 + w;      // exact: gridDim.x = NN/4

    const int deg = cnt[n];
    const int2* bk = bucket + (size_t)n * CAP;
    const __bf16* wb = wbf + hi * 256 + l31 * 8;   // + g*512 per group

    float msgr[16];
    #pragma unroll
    for (int r = 0; r < 16; ++r) msgr[r] = 0.0f;

    for (int c0 = 0; c0 < deg; c0 += 32) {
        const int idx  = c0 + l31;
        const bool act = idx < deg;
        const int2 es  = bk[act ? idx : deg - 1];   // {e, src}, clamped in-bucket
        const int e    = es.x;
        const int src  = es.y;

        const f32x4* eap = (const f32x4*)(ea + (size_t)e * 16 + hi * 8);
        f32x4 f0 = eap[0];
        f32x4 f1 = eap[1];
        bf16x8 bfrag;
        bfrag[0] = (__bf16)f0.x; bfrag[1] = (__bf16)f0.y;
        bfrag[2] = (__bf16)f0.z; bfrag[3] = (__bf16)f0.w;
        bfrag[4] = (__bf16)f1.x; bfrag[5] = (__bf16)f1.y;
        bfrag[6] = (__bf16)f1.z; bfrag[7] = (__bf16)f1.w;

        const float4* xp = (const float4*)(x + (size_t)src * 32);

        // opaque base: defeats LICM/CSE of the af/ci reads across chunks.
        int base = 0;
        asm volatile("" : "+v"(base));

        #pragma unroll
        for (int cbq = 0; cbq < 8; ++cbq) {
            float4 xq = xp[cbq];
            if (!act) { xq.x = 0.0f; xq.y = 0.0f; xq.z = 0.0f; xq.w = 0.0f; }
            #pragma unroll
            for (int c4 = 0; c4 < 4; ++c4) {
                const int g = cbq * 4 + c4;
                bf16x8 af = *(const bf16x8*)(wb + (size_t)(base + g) * 512);
                f32x16 ci = *(const f32x16*)(&BPF[base + g][hi][0]);
                f32x16 acc = __builtin_amdgcn_mfma_f32_32x32x16_bf16(af, bfrag, ci, 0, 0, 0);
                const float xv = (c4 == 0) ? xq.x : (c4 == 1) ? xq.y : (c4 == 2) ? xq.z : xq.w;
                #pragma unroll
                for (int r = 0; r < 16; ++r)
                    msgr[r] += fmaxf(acc[r], 0.0f) * xv;
                if (c4 & 1) __builtin_amdgcn_sched_barrier(0);  // 2-group window
            }
        }
    }

    // reduce across the 32 slot-lanes within each hi-half (masks < 32 never cross)
    #pragma unroll
    for (int m = 1; m <= 16; m <<= 1) {
        #pragma unroll
        for (int r = 0; r < 16; ++r)
            msgr[r] += __shfl_xor(msgr[r], m, 64);
    }

    const float rdeg = (deg > 0) ? (1.0f / (float)deg) : 0.0f;
    if (l31 == 0) {
        #pragma unroll
        for (int r = 0; r < 16; ++r) {
            const int o = (r & 3) + 8 * (r >> 2) + 4 * hi;
            msum[w][o] = msgr[r] * rdeg;
        }
    }
    __syncthreads();

    // epilogue: out[n][o] = mean_msg[o] + bias[o] + sum_i x[n][i]*root[i][o]
    const float xv = x[(size_t)n * 32 + l31];
    if (hi == 0) {
        float m = msum[w][l31] + bias_s[l31];
        #pragma unroll
        for (int i = 0; i < 32; ++i)
            m += __shfl(xv, i, 64) * root_s[i][l31];
        out[(size_t)n * 32 + l31] = m;
    }
}

// ======================= launch =======================
extern "C" void kernel_launch(void* const* d_in, const int* in_sizes, int n_in,
                              void* d_out, int out_size, void* d_ws, size_t ws_size,
                              hipStream_t stream) {
    const float* x    = (const float*)d_in[0];
    const int*   eidx = (const int*)d_in[1];     // [2][NE]
    const float* ea   = (const float*)d_in[2];   // [NE][16]
    const float* W    = (const float*)d_in[3];   // [16][1024]
    const float* be   = (const float*)d_in[4];   // [1024]
    const float* root = (const float*)d_in[5];   // [32][32]
    const float* bias = (const float*)d_in[6];   // [32]
    float* out = (float*)d_out;

    // ws: cnt[NN] ints | bucket int2[NN*CAP] | wbf bf16[16384]
    int*    cnt    = (int*)d_ws;
    int2*   bucket = (int2*)((char*)d_ws + 40000);
    __bf16* wbf    = (__bf16*)((char*)d_ws + 40000 + (size_t)NN * CAP * 8);

    hipMemsetAsync(cnt, 0, NN * sizeof(int), stream);
    scatter_bucket_kernel<<<641, 256, 0, stream>>>(eidx, cnt, bucket, W, wbf);
    edge_node_kernel<<<NN / 4, 256, 0, stream>>>(x, ea, wbf, be, root, bias,
                                                 cnt, bucket, out);
}